// Round 1
// baseline (415.734 us; speedup 1.0000x reference)
//
#include <hip/hip_runtime.h>
#include <stdint.h>

#define TSEQ 2048
#define NB   4
#define NH   16
#define HD   64
#define EMB  1024
#define ROWS (TSEQ*NB)   // 8192

typedef __attribute__((ext_vector_type(8))) short bf16x8;
typedef __attribute__((ext_vector_type(4))) short bf16x4;
typedef __attribute__((ext_vector_type(4))) float f32x4;

__device__ __forceinline__ short f2bf(float x) {
    uint32_t u = __builtin_bit_cast(uint32_t, x);
    u += 0x7fffu + ((u >> 16) & 1u);     // RNE
    return (short)(u >> 16);
}

// ---------------- prep: weights fp32->bf16, mask -> additive fp32 bias ----------------
__global__ __launch_bounds__(256)
void prep_kernel(const float* __restrict__ Wq, const float* __restrict__ Wk,
                 const float* __restrict__ Wv, const float* __restrict__ Wo,
                 short* __restrict__ Wbf,
                 const int* __restrict__ mask, float* __restrict__ bias)
{
    int gid = blockIdx.x * 256 + threadIdx.x;      // 4096 blocks -> 1048576 float4 groups
    int wsel = gid >> 18;                          // 262144 float4 per weight
    const float* __restrict__ src = (wsel == 0) ? Wq : (wsel == 1) ? Wk : (wsel == 2) ? Wv : Wo;
    float4 v = ((const float4*)src)[gid & 262143];
    bf16x4 o = { f2bf(v.x), f2bf(v.y), f2bf(v.z), f2bf(v.w) };
    ((bf16x4*)Wbf)[gid] = o;
    if (gid < NB * TSEQ)
        bias[gid] = mask[gid] ? -1e9f : 0.0f;
}

// ---------------- projection GEMM: C = X @ W^T, X fp32 (8192x1024), W bf16 (1024x1024) ----------------
// epilogue scatters bf16 into (B,H,T,64); z picks q/k/v; Q scaled by 0.125
__global__ __launch_bounds__(256, 2)
void proj_gemm(const float* __restrict__ Xq, const float* __restrict__ Xk, const float* __restrict__ Xv,
               const short* __restrict__ Wbf,
               short* __restrict__ Qw, short* __restrict__ Kw, short* __restrict__ Vw)
{
    __shared__ __align__(16) short As[128*40];
    __shared__ __align__(16) short Bs[128*40];
    const int z = blockIdx.z;
    const float* __restrict__ A = (z == 0) ? Xq : (z == 1) ? Xk : Xv;
    const short* __restrict__ Bw = Wbf + (size_t)z * (EMB*EMB);
    short* __restrict__ dst = (z == 0) ? Qw : (z == 1) ? Kw : Vw;
    const float scale = (z == 0) ? 0.125f : 1.0f;   // 1/sqrt(64) folded into Q

    const int tid = threadIdx.x;
    const int lane = tid & 63, wv = tid >> 6;
    const int wm = wv >> 1, wn = wv & 1;
    const int g = lane >> 4, c = lane & 15;
    const int m0 = blockIdx.x * 128, n0 = blockIdx.y * 128;

    f32x4 acc[4][4] = {};

    for (int kt = 0; kt < EMB; kt += 32) {
        // stage A (fp32 -> bf16): 128x32 tile, 4 float4 per thread
        #pragma unroll
        for (int i = 0; i < 4; i++) {
            int idx = tid + i * 256;
            int row = idx >> 3, c4 = idx & 7;
            float4 v = *(const float4*)(A + (size_t)(m0 + row) * EMB + kt + c4 * 4);
            bf16x4 o = { f2bf(v.x), f2bf(v.y), f2bf(v.z), f2bf(v.w) };
            *(bf16x4*)(&As[row * 40 + c4 * 4]) = o;
        }
        // stage B (bf16): 128x32 tile, 2 x 16B per thread
        #pragma unroll
        for (int i = 0; i < 2; i++) {
            int idx = tid + i * 256;
            int row = idx >> 2, c8 = idx & 3;
            *(int4*)(&Bs[row * 40 + c8 * 8]) = *(const int4*)(Bw + (size_t)(n0 + row) * EMB + kt + c8 * 8);
        }
        __syncthreads();
        bf16x8 a[4], bfr[4];
        #pragma unroll
        for (int mt = 0; mt < 4; mt++) a[mt]   = *(const bf16x8*)(&As[(wm*64 + mt*16 + c) * 40 + g * 8]);
        #pragma unroll
        for (int nt = 0; nt < 4; nt++) bfr[nt] = *(const bf16x8*)(&Bs[(wn*64 + nt*16 + c) * 40 + g * 8]);
        #pragma unroll
        for (int mt = 0; mt < 4; mt++)
            #pragma unroll
            for (int nt = 0; nt < 4; nt++)
                acc[mt][nt] = __builtin_amdgcn_mfma_f32_16x16x32_bf16(a[mt], bfr[nt], acc[mt][nt], 0, 0, 0);
        __syncthreads();
    }
    // epilogue: row r=(t,b) r=t*4+b ; col f=(h,dk) -> dst[((b*16+h)*2048+t)*64+dk]
    #pragma unroll
    for (int mt = 0; mt < 4; mt++)
        #pragma unroll
        for (int nt = 0; nt < 4; nt++)
            #pragma unroll
            for (int r = 0; r < 4; r++) {
                int row = m0 + wm*64 + mt*16 + g*4 + r;
                int col = n0 + wn*64 + nt*16 + c;
                int t = row >> 2, bb = row & 3, h = col >> 6, dk = col & 63;
                dst[(((size_t)(bb*16 + h) * TSEQ + t) << 6) + dk] = f2bf(acc[mt][nt][r] * scale);
            }
}

// ---------------- V transpose: (bh, t, d) -> (bh, d, t) ----------------
__global__ __launch_bounds__(256)
void transpose_v(const short* __restrict__ V, short* __restrict__ Vt)
{
    __shared__ __align__(16) short tile[64*72];
    const int bh = blockIdx.y, t0 = blockIdx.x * 64;
    const int tid = threadIdx.x;
    const short* __restrict__ Vh = V + (size_t)bh * TSEQ * HD;
    #pragma unroll
    for (int i = 0; i < 2; i++) {
        int idx = tid + i * 256, row = idx >> 3, cc = idx & 7;
        *(int4*)(&tile[row * 72 + cc * 8]) = *(const int4*)(Vh + (size_t)(t0 + row) * HD + cc * 8);
    }
    __syncthreads();
    #pragma unroll
    for (int i = 0; i < 2; i++) {
        int idx = tid + i * 256, dv = idx >> 3, cc = idx & 7;
        bf16x8 o;
        #pragma unroll
        for (int j = 0; j < 8; j++) o[j] = tile[(cc * 8 + j) * 72 + dv];
        *(bf16x8*)(Vt + ((size_t)bh * HD + dv) * TSEQ + t0 + cc * 8) = o;
    }
}

// ---------------- flash attention (transposed-score formulation) ----------------
// per block: one (b,h), 64 q rows; 4 waves x 16 q each. S^T = K @ Q^T (bias-init = mask),
// online softmax per q (lane-scalar m,l), O^T += V^T @ P^T, final LDS transpose for store.
__global__ __launch_bounds__(256, 2)
void attn_kernel(const short* __restrict__ Q, const short* __restrict__ K,
                 const short* __restrict__ Vt, const float* __restrict__ bias,
                 short* __restrict__ O)
{
    __shared__ __align__(16) short Qs [64*72];
    __shared__ __align__(16) short Ks [64*72];
    __shared__ __align__(16) short Vts[64*72];
    __shared__ __align__(16) short Ps [64*72];

    const int bh = blockIdx.y;
    const int q0 = blockIdx.x * 64;
    const int tid = threadIdx.x, lane = tid & 63, wv = tid >> 6;
    const int g = lane >> 4, c = lane & 15;
    const short* __restrict__ Qh  = Q  + (size_t)bh * TSEQ * HD;
    const short* __restrict__ Kh  = K  + (size_t)bh * TSEQ * HD;
    const short* __restrict__ Vth = Vt + (size_t)bh * HD * TSEQ;
    const float* __restrict__ biasb = bias + (bh >> 4) * TSEQ;

    // stage Q tile (64 x 64)
    #pragma unroll
    for (int i = 0; i < 2; i++) {
        int idx = tid + i * 256, row = idx >> 3, cc = idx & 7;
        *(int4*)(&Qs[row * 72 + cc * 8]) = *(const int4*)(Qh + (size_t)(q0 + row) * HD + cc * 8);
    }

    float m_prev = -1e30f, l_sum = 0.0f;
    f32x4 oacc[4] = {};
    const int qrow = (wv * 16 + c) * 72;   // this lane's q row in Qs/Ps

    for (int tk0 = 0; tk0 < TSEQ; tk0 += 64) {
        // stage K (t,d) and V^T (d,t) tiles
        #pragma unroll
        for (int i = 0; i < 2; i++) {
            int idx = tid + i * 256, row = idx >> 3, cc = idx & 7;
            *(int4*)(&Ks [row * 72 + cc * 8]) = *(const int4*)(Kh  + (size_t)(tk0 + row) * HD + cc * 8);
            *(int4*)(&Vts[row * 72 + cc * 8]) = *(const int4*)(Vth + (size_t)row * TSEQ + tk0 + cc * 8);
        }
        __syncthreads();

        // S^T (64 tk x 16 q per wave), accumulator initialized with mask bias
        f32x4 sacc[4];
        #pragma unroll
        for (int mt = 0; mt < 4; mt++)
            sacc[mt] = *(const f32x4*)(biasb + tk0 + mt * 16 + g * 4);
        bf16x8 qf[2];
        #pragma unroll
        for (int ks = 0; ks < 2; ks++) qf[ks] = *(const bf16x8*)(&Qs[qrow + ks * 32 + g * 8]);
        #pragma unroll
        for (int ks = 0; ks < 2; ks++)
            #pragma unroll
            for (int mt = 0; mt < 4; mt++) {
                bf16x8 kf = *(const bf16x8*)(&Ks[(mt * 16 + c) * 72 + ks * 32 + g * 8]);
                sacc[mt] = __builtin_amdgcn_mfma_f32_16x16x32_bf16(kf, qf[ks], sacc[mt], 0, 0, 0);
            }

        // online softmax for this lane's q column
        float mx = -1e30f;
        #pragma unroll
        for (int mt = 0; mt < 4; mt++)
            #pragma unroll
            for (int r = 0; r < 4; r++) mx = fmaxf(mx, sacc[mt][r]);
        mx = fmaxf(mx, __shfl_xor(mx, 16));
        mx = fmaxf(mx, __shfl_xor(mx, 32));
        float m_new = fmaxf(m_prev, mx);
        float alpha = __expf(m_prev - m_new);
        float ps = 0.0f;
        float p[4][4];
        #pragma unroll
        for (int mt = 0; mt < 4; mt++)
            #pragma unroll
            for (int r = 0; r < 4; r++) {
                float e = __expf(sacc[mt][r] - m_new);
                p[mt][r] = e; ps += e;
            }
        ps += __shfl_xor(ps, 16);
        ps += __shfl_xor(ps, 32);
        l_sum = l_sum * alpha + ps;
        m_prev = m_new;
        #pragma unroll
        for (int mt = 0; mt < 4; mt++)
            #pragma unroll
            for (int r = 0; r < 4; r++) oacc[mt][r] *= alpha;

        // P^T round-trip: lane's 4 reg values are 4 consecutive tk -> one b64 write per mt
        #pragma unroll
        for (int mt = 0; mt < 4; mt++) {
            bf16x4 pk = { f2bf(p[mt][0]), f2bf(p[mt][1]), f2bf(p[mt][2]), f2bf(p[mt][3]) };
            *(bf16x4*)(&Ps[qrow + mt * 16 + g * 4]) = pk;
        }
        __builtin_amdgcn_sched_barrier(0);  // keep P writes before P reads (same wave, cross-lane)

        // O^T += V^T @ P^T
        #pragma unroll
        for (int ks = 0; ks < 2; ks++) {
            bf16x8 pf = *(const bf16x8*)(&Ps[qrow + ks * 32 + g * 8]);
            #pragma unroll
            for (int mt = 0; mt < 4; mt++) {
                bf16x8 vf = *(const bf16x8*)(&Vts[(mt * 16 + c) * 72 + ks * 32 + g * 8]);
                oacc[mt] = __builtin_amdgcn_mfma_f32_16x16x32_bf16(vf, pf, oacc[mt], 0, 0, 0);
            }
        }
        __syncthreads();
    }

    // finalize: O^T/l -> LDS (reuse Ks) as [q_local][dv], then coalesced store
    float inv = 1.0f / l_sum;
    #pragma unroll
    for (int mt = 0; mt < 4; mt++) {
        bf16x4 ok = { f2bf(oacc[mt][0] * inv), f2bf(oacc[mt][1] * inv),
                      f2bf(oacc[mt][2] * inv), f2bf(oacc[mt][3] * inv) };
        *(bf16x4*)(&Ks[qrow + mt * 16 + g * 4]) = ok;
    }
    __syncthreads();
    const int b_ = bh >> 4, h_ = bh & 15;
    #pragma unroll
    for (int i = 0; i < 2; i++) {
        int idx = tid + i * 256, row = idx >> 3, cc = idx & 7;
        *(int4*)(O + (((size_t)(q0 + row) * NB + b_) << 10) + h_ * 64 + cc * 8) =
            *(const int4*)(&Ks[row * 72 + cc * 8]);
    }
}

// ---------------- output GEMM: Y = O(bf16, 8192x1024) @ Wo^T -> fp32 ----------------
__global__ __launch_bounds__(256, 2)
void out_gemm(const short* __restrict__ A, const short* __restrict__ Bw, float* __restrict__ C)
{
    __shared__ __align__(16) short As[128*40];
    __shared__ __align__(16) short Bs[128*40];
    const int tid = threadIdx.x;
    const int lane = tid & 63, wv = tid >> 6;
    const int wm = wv >> 1, wn = wv & 1;
    const int g = lane >> 4, c = lane & 15;
    const int m0 = blockIdx.x * 128, n0 = blockIdx.y * 128;

    f32x4 acc[4][4] = {};
    for (int kt = 0; kt < EMB; kt += 32) {
        #pragma unroll
        for (int i = 0; i < 2; i++) {
            int idx = tid + i * 256;
            int row = idx >> 2, c8 = idx & 3;
            *(int4*)(&As[row * 40 + c8 * 8]) = *(const int4*)(A  + (size_t)(m0 + row) * EMB + kt + c8 * 8);
            *(int4*)(&Bs[row * 40 + c8 * 8]) = *(const int4*)(Bw + (size_t)(n0 + row) * EMB + kt + c8 * 8);
        }
        __syncthreads();
        bf16x8 a[4], bfr[4];
        #pragma unroll
        for (int mt = 0; mt < 4; mt++) a[mt]   = *(const bf16x8*)(&As[(wm*64 + mt*16 + c) * 40 + g * 8]);
        #pragma unroll
        for (int nt = 0; nt < 4; nt++) bfr[nt] = *(const bf16x8*)(&Bs[(wn*64 + nt*16 + c) * 40 + g * 8]);
        #pragma unroll
        for (int mt = 0; mt < 4; mt++)
            #pragma unroll
            for (int nt = 0; nt < 4; nt++)
                acc[mt][nt] = __builtin_amdgcn_mfma_f32_16x16x32_bf16(a[mt], bfr[nt], acc[mt][nt], 0, 0, 0);
        __syncthreads();
    }
    #pragma unroll
    for (int mt = 0; mt < 4; mt++)
        #pragma unroll
        for (int nt = 0; nt < 4; nt++)
            #pragma unroll
            for (int r = 0; r < 4; r++) {
                int row = m0 + wm*64 + mt*16 + g*4 + r;
                int col = n0 + wn*64 + nt*16 + c;
                C[(size_t)row * EMB + col] = acc[mt][nt][r];
            }
}

extern "C" void kernel_launch(void* const* d_in, const int* in_sizes, int n_in,
                              void* d_out, int out_size, void* d_ws, size_t ws_size,
                              hipStream_t stream)
{
    const float* q    = (const float*)d_in[0];
    const float* k    = (const float*)d_in[1];
    const float* v    = (const float*)d_in[2];
    const int*   mask = (const int*)  d_in[3];
    const float* Wq   = (const float*)d_in[4];
    const float* Wk   = (const float*)d_in[5];
    const float* Wv   = (const float*)d_in[6];
    const float* Wo   = (const float*)d_in[7];
    float* out = (float*)d_out;

    char* ws = (char*)d_ws;
    short* Wbf  = (short*)(ws);                      //  8,388,608 B (Wq,Wk,Wv,Wo bf16)
    short* Qws  = (short*)(ws +  8388608);           // 16,777,216 B (B,H,T,64)
    short* Kws  = (short*)(ws + 25165824);           // 16,777,216 B
    short* Vws  = (short*)(ws + 41943040);           // 16,777,216 B
    short* Vtws = (short*)(ws + 58720256);           // 16,777,216 B (B,H,64,T)
    short* Ows  = (short*)(ws + 75497472);           // 16,777,216 B (T,B,E)
    float* bias = (float*)(ws + 92274688);           //     32,768 B

    prep_kernel<<<4096, 256, 0, stream>>>(Wq, Wk, Wv, Wo, Wbf, mask, bias);
    proj_gemm<<<dim3(ROWS/128, EMB/128, 3), 256, 0, stream>>>(q, k, v, Wbf, Qws, Kws, Vws);
    transpose_v<<<dim3(TSEQ/64, NB*NH), 256, 0, stream>>>(Vws, Vtws);
    attn_kernel<<<dim3(TSEQ/64, NB*NH), 256, 0, stream>>>(Qws, Kws, Vtws, bias, Ows);
    out_gemm<<<dim3(ROWS/128, EMB/128), 256, 0, stream>>>(Ows, Wbf + (size_t)3*EMB*EMB, out);
}